// Round 1
// baseline (1127.922 us; speedup 1.0000x reference)
//
#include <hip/hip_runtime.h>
#include <stdint.h>

#define T_TOK 8192
#define D_HID 1024
#define F_INT 4096
#define NEXP 8
#define NT2 (T_TOK*2)
#define BM 128
#define MAX_TILES (NT2/BM + NEXP)
#define CBANKS 64

typedef __attribute__((ext_vector_type(4))) float f32x4;
typedef __attribute__((ext_vector_type(8))) __bf16 bf16x8;

__device__ __forceinline__ unsigned short f2bf(float x) {
  unsigned int u = __float_as_uint(x);
  u = u + 0x7FFFu + ((u >> 16) & 1u);
  return (unsigned short)(u >> 16);
}

__device__ __forceinline__ void gload_lds16(const void* g, void* l) {
  __builtin_amdgcn_global_load_lds(
      (const __attribute__((address_space(1))) unsigned int*)g,
      (__attribute__((address_space(3))) unsigned int*)l, 16, 0, 0);
}

// ---------------- fp32 -> bf16 conversion ----------------
__global__ __launch_bounds__(256) void k_cvt(const float* __restrict__ in,
                                             unsigned short* __restrict__ out, long n) {
  long i = ((long)blockIdx.x * 256 + threadIdx.x) * 4;
  long stride = (long)gridDim.x * 1024;
  for (; i < n; i += stride) {
    float4 v = *(const float4*)(in + i);
    union { unsigned short s[4]; uint2 v2; } o;
    o.s[0] = f2bf(v.x); o.s[1] = f2bf(v.y); o.s[2] = f2bf(v.z); o.s[3] = f2bf(v.w);
    *(uint2*)(out + i) = o.v2;
  }
}

// ---------------- router: one wave per token, fp64 accumulation ----------------
__global__ __launch_bounds__(256) void k_router(const float* __restrict__ h,
                                                const float* __restrict__ rw,
                                                int* __restrict__ cntB,
                                                float* __restrict__ psumB,
                                                int* __restrict__ topk_e,
                                                float* __restrict__ topk_w) {
  int t = blockIdx.x * 4 + (threadIdx.x >> 6);
  int l = threadIdx.x & 63;
  const float* hr = h + (size_t)t * D_HID;
  double acc[NEXP];
#pragma unroll
  for (int e = 0; e < NEXP; e++) acc[e] = 0.0;
  for (int i = l; i < D_HID; i += 64) {
    double x = (double)hr[i];
    const float4* r4 = (const float4*)(rw + (size_t)i * NEXP);
    float4 a = r4[0], b = r4[1];
    acc[0] += x * a.x; acc[1] += x * a.y; acc[2] += x * a.z; acc[3] += x * a.w;
    acc[4] += x * b.x; acc[5] += x * b.y; acc[6] += x * b.z; acc[7] += x * b.w;
  }
#pragma unroll
  for (int m = 32; m >= 1; m >>= 1) {
#pragma unroll
    for (int e = 0; e < NEXP; e++) acc[e] += __shfl_xor(acc[e], m, 64);
  }
  if (l == 0) {
    double mx = acc[0];
#pragma unroll
    for (int e = 1; e < NEXP; e++) mx = fmax(mx, acc[e]);
    double p[NEXP], s = 0.0;
#pragma unroll
    for (int e = 0; e < NEXP; e++) { p[e] = exp(acc[e] - mx); s += p[e]; }
    int i0 = 0;
#pragma unroll
    for (int e = 1; e < NEXP; e++) if (p[e] > p[i0]) i0 = e;
    int i1 = (i0 == 0) ? 1 : 0;
#pragma unroll
    for (int e = 0; e < NEXP; e++) if (e != i0 && p[e] > p[i1]) i1 = e;
    double w0 = p[i0] / (p[i0] + p[i1]);
    topk_e[t] = i0 | (i1 << 8);
    topk_w[2 * t] = (float)w0;
    topk_w[2 * t + 1] = (float)(1.0 - w0);
    int bank = t & (CBANKS - 1);
    atomicAdd(&cntB[i0 * CBANKS + bank], 1);
    atomicAdd(&cntB[i1 * CBANKS + bank], 1);
    float inv = (float)(1.0 / s);
#pragma unroll
    for (int e = 0; e < NEXP; e++) atomicAdd(&psumB[e * CBANKS + bank], (float)p[e] * inv);
  }
}

// ---------------- scan: offsets, tile table, loss ----------------
__global__ void k_scan(const int* __restrict__ cntB, const float* __restrict__ psumB,
                       int* __restrict__ offs, int4* __restrict__ tiles,
                       int* __restrict__ meta, float* __restrict__ loss_out,
                       int* __restrict__ cnt2) {
  if (threadIdx.x != 0 || blockIdx.x != 0) return;
  int off = 0, tc = 0;
  double loss = 0.0;
  for (int e = 0; e < NEXP; e++) {
    int c = 0; float ps = 0.f;
    for (int b = 0; b < CBANKS; b++) { c += cntB[e * CBANKS + b]; ps += psumB[e * CBANKS + b]; }
    loss += ((double)c / (double)T_TOK) * ((double)ps / (double)T_TOK);
    offs[e] = off;
    int nt = (c + BM - 1) / BM;
    for (int j = 0; j < nt; j++) {
      int rem = c - j * BM;
      tiles[tc] = make_int4(e, off + j * BM, rem < BM ? rem : BM, 0);
      tc++;
    }
    off += c;
    cnt2[e] = 0;
  }
  offs[NEXP] = off;
  meta[0] = tc;
  loss_out[0] = (float)(loss * (double)NEXP);
}

// ---------------- scatter tokens into expert-grouped order ----------------
__global__ __launch_bounds__(256) void k_scatter(const int* __restrict__ topk_e,
                                                 const float* __restrict__ topk_w,
                                                 const int* __restrict__ offs,
                                                 int* __restrict__ cnt2,
                                                 int* __restrict__ rowtok,
                                                 float* __restrict__ roww) {
  int t = blockIdx.x * 256 + threadIdx.x;
  if (t >= T_TOK) return;
  int ee = topk_e[t];
#pragma unroll
  for (int k = 0; k < 2; k++) {
    int e = (ee >> (8 * k)) & 255;
    int pos = offs[e] + atomicAdd(&cnt2[e], 1);
    rowtok[pos] = t;
    roww[pos] = topk_w[2 * t + k];
  }
}

// ---------------- gate/up dual GEMM + silu -> G (bf16) ----------------
template <int WBF16>
__global__ __launch_bounds__(256) void k_gateup(
    const unsigned short* __restrict__ hb,
    const void* __restrict__ gwp, const void* __restrict__ uwp,
    const int4* __restrict__ tiles, const int* __restrict__ meta,
    const int* __restrict__ rowtok,
    unsigned short* __restrict__ G,
    int fc_base, int FC) {
  if ((int)blockIdx.x >= meta[0]) return;
  int4 td = tiles[blockIdx.x];
  int eid = td.x, row0 = td.y, nrows = td.z;
  int col0 = fc_base + blockIdx.y * 64;  // global col in F
  int lcol0 = blockIdx.y * 64;           // col within G chunk

  __shared__ __align__(16) unsigned short Alds[BM][32];
  __shared__ __align__(16) unsigned short Blds[2][64][32];

  int tid = threadIdx.x;
  int l = tid & 63, wid = tid >> 6;
  int wr = wid >> 1, wc = wid & 1;

  const char* gA0;
  const char* gA1;
  {
    int rr0 = wid * 32 + (l >> 2);
    int rr1 = rr0 + 16;
    int tok0 = rowtok[row0 + ((rr0 < nrows) ? rr0 : 0)];
    int tok1 = rowtok[row0 + ((rr1 < nrows) ? rr1 : 0)];
    gA0 = (const char*)hb + ((size_t)tok0 * D_HID + (size_t)(l & 3) * 8) * 2;
    gA1 = (const char*)hb + ((size_t)tok1 * D_HID + (size_t)(l & 3) * 8) * 2;
  }
  int bmat = tid >> 7;
  int bidx = tid & 127;
  int bn = bidx & 63;
  int bkh = (bidx >> 6) << 4;  // 0 or 16
  const void* wsel = bmat ? uwp : gwp;
  size_t wb0 = (size_t)eid * D_HID * F_INT + (size_t)(col0 + bn);

  f32x4 accg[4][2], accu[4][2];
#pragma unroll
  for (int m = 0; m < 4; m++)
#pragma unroll
    for (int n = 0; n < 2; n++) {
      accg[m][n] = f32x4{0.f, 0.f, 0.f, 0.f};
      accu[m][n] = f32x4{0.f, 0.f, 0.f, 0.f};
    }

  for (int k0 = 0; k0 < D_HID; k0 += 32) {
    unsigned short vv[16];
    if (WBF16) {
      const unsigned short* wp = (const unsigned short*)wsel;
#pragma unroll
      for (int j = 0; j < 16; j++) vv[j] = wp[wb0 + (size_t)(k0 + bkh + j) * F_INT];
    } else {
      const float* wp = (const float*)wsel;
#pragma unroll
      for (int j = 0; j < 16; j++) vv[j] = f2bf(wp[wb0 + (size_t)(k0 + bkh + j) * F_INT]);
    }
    __syncthreads();  // previous tile fully consumed
    gload_lds16(gA0 + (size_t)k0 * 2, &Alds[wid * 32][0]);
    gload_lds16(gA1 + (size_t)k0 * 2, &Alds[wid * 32 + 16][0]);
    union { unsigned short s[8]; uint4 q; } p0, p1;
#pragma unroll
    for (int j = 0; j < 8; j++) { p0.s[j] = vv[j]; p1.s[j] = vv[j + 8]; }
    *(uint4*)&Blds[bmat][bn][bkh] = p0.q;
    *(uint4*)&Blds[bmat][bn][bkh + 8] = p1.q;
    __syncthreads();  // staging complete (implicit vmcnt/lgkm drain)

    bf16x8 af[4], bg[2], bu[2];
#pragma unroll
    for (int m = 0; m < 4; m++)
      af[m] = *(const bf16x8*)&Alds[wr * 64 + m * 16 + (l & 15)][(l >> 4) * 8];
#pragma unroll
    for (int n = 0; n < 2; n++) {
      bg[n] = *(const bf16x8*)&Blds[0][wc * 32 + n * 16 + (l & 15)][(l >> 4) * 8];
      bu[n] = *(const bf16x8*)&Blds[1][wc * 32 + n * 16 + (l & 15)][(l >> 4) * 8];
    }
#pragma unroll
    for (int m = 0; m < 4; m++)
#pragma unroll
      for (int n = 0; n < 2; n++) {
        accg[m][n] = __builtin_amdgcn_mfma_f32_16x16x32_bf16(af[m], bg[n], accg[m][n], 0, 0, 0);
        accu[m][n] = __builtin_amdgcn_mfma_f32_16x16x32_bf16(af[m], bu[n], accu[m][n], 0, 0, 0);
      }
  }

  int lr = (l >> 4) * 4, lc = l & 15;
#pragma unroll
  for (int m = 0; m < 4; m++)
#pragma unroll
    for (int j = 0; j < 4; j++) {
      int r = wr * 64 + m * 16 + lr + j;
      if (r < nrows) {
        size_t rowbase = (size_t)(row0 + r) * FC + lcol0 + wc * 32 + lc;
#pragma unroll
        for (int n = 0; n < 2; n++) {
          float g = accg[m][n][j], u = accu[m][n][j];
          float sv = g / (1.0f + __expf(-g));
          G[rowbase + n * 16] = f2bf(sv * u);
        }
      }
    }
}

// ---------------- down GEMM, scaled scatter-add into output ----------------
template <int WBF16>
__global__ __launch_bounds__(256) void k_down(
    const unsigned short* __restrict__ G,
    const void* __restrict__ dwp,
    const int4* __restrict__ tiles, const int* __restrict__ meta,
    const int* __restrict__ rowtok, const float* __restrict__ roww,
    float* __restrict__ out,
    int fc_base, int FC) {
  if ((int)blockIdx.x >= meta[0]) return;
  int4 td = tiles[blockIdx.x];
  int eid = td.x, row0 = td.y, nrows = td.z;
  int col0 = blockIdx.y * 64;  // col in D

  __shared__ __align__(16) unsigned short Alds[BM][32];
  __shared__ __align__(16) unsigned short Blds[64][32];

  int tid = threadIdx.x;
  int l = tid & 63, wid = tid >> 6;
  int wr = wid >> 1, wc = wid & 1;

  const char* gA0 = (const char*)G +
      ((size_t)(row0 + wid * 32 + (l >> 2)) * FC + (size_t)(l & 3) * 8) * 2;
  const char* gA1 = gA0 + (size_t)16 * FC * 2;

  int bn = tid & 63;
  int bkq = (tid >> 6) << 3;  // 0,8,16,24
  size_t wb0 = (size_t)eid * F_INT * D_HID + (size_t)(col0 + bn);

  f32x4 acc[4][2];
#pragma unroll
  for (int m = 0; m < 4; m++)
#pragma unroll
    for (int n = 0; n < 2; n++) acc[m][n] = f32x4{0.f, 0.f, 0.f, 0.f};

  for (int k0 = 0; k0 < FC; k0 += 32) {
    unsigned short vv[8];
    if (WBF16) {
      const unsigned short* wp = (const unsigned short*)dwp;
#pragma unroll
      for (int j = 0; j < 8; j++) vv[j] = wp[wb0 + (size_t)(fc_base + k0 + bkq + j) * D_HID];
    } else {
      const float* wp = (const float*)dwp;
#pragma unroll
      for (int j = 0; j < 8; j++) vv[j] = f2bf(wp[wb0 + (size_t)(fc_base + k0 + bkq + j) * D_HID]);
    }
    __syncthreads();
    gload_lds16(gA0 + (size_t)k0 * 2, &Alds[wid * 32][0]);
    gload_lds16(gA1 + (size_t)k0 * 2, &Alds[wid * 32 + 16][0]);
    union { unsigned short s[8]; uint4 q; } p0;
#pragma unroll
    for (int j = 0; j < 8; j++) p0.s[j] = vv[j];
    *(uint4*)&Blds[bn][bkq] = p0.q;
    __syncthreads();

    bf16x8 af[4], bf[2];
#pragma unroll
    for (int m = 0; m < 4; m++)
      af[m] = *(const bf16x8*)&Alds[wr * 64 + m * 16 + (l & 15)][(l >> 4) * 8];
#pragma unroll
    for (int n = 0; n < 2; n++)
      bf[n] = *(const bf16x8*)&Blds[wc * 32 + n * 16 + (l & 15)][(l >> 4) * 8];
#pragma unroll
    for (int m = 0; m < 4; m++)
#pragma unroll
      for (int n = 0; n < 2; n++)
        acc[m][n] = __builtin_amdgcn_mfma_f32_16x16x32_bf16(af[m], bf[n], acc[m][n], 0, 0, 0);
  }

  int lr = (l >> 4) * 4, lc = l & 15;
#pragma unroll
  for (int m = 0; m < 4; m++)
#pragma unroll
    for (int j = 0; j < 4; j++) {
      int r = wr * 64 + m * 16 + lr + j;
      if (r < nrows) {
        float w = roww[row0 + r];
        int tok = rowtok[row0 + r];
#pragma unroll
        for (int n = 0; n < 2; n++)
          atomicAdd(&out[(size_t)tok * D_HID + col0 + wc * 32 + n * 16 + lc],
                    acc[m][n][j] * w);
      }
    }
}

extern "C" void kernel_launch(void* const* d_in, const int* in_sizes, int n_in,
                              void* d_out, int out_size, void* d_ws, size_t ws_size,
                              hipStream_t stream) {
  (void)in_sizes; (void)n_in;
  const float* h  = (const float*)d_in[0];
  const float* rw = (const float*)d_in[1];
  const float* gw = (const float*)d_in[2];
  const float* uw = (const float*)d_in[3];
  const float* dw = (const float*)d_in[4];
  float* out = (float*)d_out;

  char* base = (char*)d_ws;
  size_t off = 0;
  auto alloc = [&](size_t b) -> char* {
    char* r = base + off;
    off += (b + 255) & ~(size_t)255;
    return r;
  };

  unsigned short* hb = (unsigned short*)alloc((size_t)T_TOK * D_HID * 2);
  int*   cntB   = (int*)alloc(NEXP * CBANKS * 4);
  float* psumB  = (float*)alloc(NEXP * CBANKS * 4);
  int*   offs   = (int*)alloc((NEXP + 1) * 4);
  int*   cnt2   = (int*)alloc(NEXP * 4);
  int*   meta   = (int*)alloc(64);
  int4*  tiles  = (int4*)alloc(MAX_TILES * sizeof(int4));
  int*   topk_e = (int*)alloc(T_TOK * 4);
  float* topk_w = (float*)alloc((size_t)T_TOK * 2 * 4);
  int*   rowtok = (int*)alloc(NT2 * 4);
  float* roww   = (float*)alloc(NT2 * 4);

  size_t zbytes = (size_t)((char*)topk_e - (char*)cntB);

  const size_t GROWS = NT2 + (size_t)BM * NEXP;  // padded-row slack
  const size_t EDF = (size_t)NEXP * D_HID * F_INT;
  const size_t wbytes = 3 * EDF * 2;
  size_t avail = (ws_size > off) ? ws_size - off : 0;
  auto gsz = [&](int nc) -> size_t { return GROWS * (size_t)(F_INT / nc) * 2; };
  int use_bf16w, nchunk;
  if      (avail >= wbytes + gsz(1) + 4096) { use_bf16w = 1; nchunk = 1; }
  else if (avail >= wbytes + gsz(4) + 4096) { use_bf16w = 1; nchunk = 4; }
  else if (avail >= gsz(1) + 4096)          { use_bf16w = 0; nchunk = 1; }
  else if (avail >= gsz(4) + 4096)          { use_bf16w = 0; nchunk = 4; }
  else                                      { use_bf16w = 0; nchunk = 16; }
  unsigned short* wb = use_bf16w ? (unsigned short*)alloc(wbytes) : (unsigned short*)0;
  int FC = F_INT / nchunk;
  unsigned short* G = (unsigned short*)alloc(GROWS * (size_t)FC * 2);

  hipMemsetAsync(d_out, 0, (size_t)out_size * 4, stream);
  hipMemsetAsync(cntB, 0, zbytes, stream);

  k_cvt<<<2048, 256, 0, stream>>>(h, hb, (long)T_TOK * D_HID);
  if (use_bf16w) {
    k_cvt<<<4096, 256, 0, stream>>>(gw, wb,            (long)EDF);
    k_cvt<<<4096, 256, 0, stream>>>(uw, wb + EDF,      (long)EDF);
    k_cvt<<<4096, 256, 0, stream>>>(dw, wb + 2 * EDF,  (long)EDF);
  }
  k_router<<<T_TOK / 4, 256, 0, stream>>>(h, rw, cntB, psumB, topk_e, topk_w);
  k_scan<<<1, 64, 0, stream>>>(cntB, psumB, offs, tiles, meta, out + (out_size - 1), cnt2);
  k_scatter<<<T_TOK / 256, 256, 0, stream>>>(topk_e, topk_w, offs, cnt2, rowtok, roww);

  for (int c = 0; c < nchunk; c++) {
    int fcb = c * FC;
    dim3 g4(MAX_TILES, FC / 64), g5(MAX_TILES, D_HID / 64);
    if (use_bf16w) {
      k_gateup<1><<<g4, 256, 0, stream>>>(hb, wb, wb + EDF, tiles, meta, rowtok, G, fcb, FC);
      k_down<1><<<g5, 256, 0, stream>>>(G, wb + 2 * EDF, tiles, meta, rowtok, roww, out, fcb, FC);
    } else {
      k_gateup<0><<<g4, 256, 0, stream>>>(hb, gw, uw, tiles, meta, rowtok, G, fcb, FC);
      k_down<0><<<g5, 256, 0, stream>>>(G, dw, tiles, meta, rowtok, roww, out, fcb, FC);
    }
  }
}